// Round 1
// baseline (275.807 us; speedup 1.0000x reference)
//
#include <hip/hip_runtime.h>
#include <math.h>

#define B_TOTAL 8192
#define NN      82
#define HH      10
#define OUTC    5
#define TSTEP   3
#define BPB     3      // batch elements per block
#define THREADS 256
#define ROWP    12     // padded LDS row stride (floats) -> 48B, keeps float4 aligned

__device__ __forceinline__ float sigmoid_(float x) {
    return 1.0f / (1.0f + __expf(-x));
}
__device__ __forceinline__ float tanh_(float x) {
    // tanh(x) = 1 - 2/(exp(2x)+1); saturates correctly at +/-1 for large |x|
    float e = __expf(2.0f * x);
    return 1.0f - 2.0f / (e + 1.0f);
}

// Pre-transpose both adjacency matrices into workspace:
// adjT[j*NN + i] = adj[i*NN + j], so the main kernel's j-loop reads are
// coalesced across lanes (lane i -> consecutive addresses).
__global__ void transpose_adj_kernel(const float* __restrict__ in_adj,
                                     const float* __restrict__ out_adj,
                                     float* __restrict__ adjT) {
    int idx = blockIdx.x * blockDim.x + threadIdx.x;
    if (idx < NN * NN) {
        int i = idx / NN;
        int j = idx - i * NN;
        adjT[j * NN + i]           = in_adj[i * NN + j];
        adjT[NN * NN + j * NN + i] = out_adj[i * NN + j];
    }
}

extern "C" __global__ __launch_bounds__(THREADS)
void ggnn_kernel(const float* __restrict__ x,
                 const float* __restrict__ adjT,
                 const float* __restrict__ w3w, const float* __restrict__ b3w,
                 const float* __restrict__ w3u, const float* __restrict__ b3u,
                 const float* __restrict__ w4w, const float* __restrict__ b4w,
                 const float* __restrict__ w5w, const float* __restrict__ b5w,
                 const float* __restrict__ w5u, const float* __restrict__ b5u,
                 const float* __restrict__ wout, const float* __restrict__ bout,
                 float* __restrict__ out0, float* __restrict__ out_fn)
{
    __shared__ __align__(16) float nodes[BPB][NN][ROWP];

    const int t     = threadIdx.x;
    const int bbase = blockIdx.x * BPB;
    const int bl    = t / NN;          // local batch element 0..2 (valid if t < 246)
    const int node  = t - bl * NN;     // node index 0..81
    const bool active = (bl < BPB) && (bbase + bl < B_TOTAL);
    const int b = bbase + bl;

    // ---- cooperative, coalesced load of this block's node states into LDS ----
    {
        int nb    = min(BPB, B_TOTAL - bbase);
        int nelem = nb * NN * HH;                       // contiguous in x
        const float* src = x + (size_t)bbase * NN * HH;
        float* dst = &nodes[0][0][0];
        for (int k = t; k < nelem; k += THREADS) {
            int row = k / HH;
            int col = k - row * HH;
            dst[row * ROWP + col] = src[k];
        }
    }
    __syncthreads();

    float fn[HH];
    if (active) {
        #pragma unroll
        for (int h = 0; h < HH; ++h) fn[h] = nodes[bl][node][h];
    }

    const float* adjT_in  = adjT;
    const float* adjT_out = adjT + NN * NN;

    for (int step = 0; step < TSTEP; ++step) {
        float ai[HH], ao[HH];
        if (active) {
            #pragma unroll
            for (int h = 0; h < HH; ++h) { ai[h] = 0.0f; ao[h] = 0.0f; }

            const float* nrow = &nodes[bl][0][0];
            #pragma unroll 4
            for (int j = 0; j < NN; ++j) {
                float win = adjT_in [j * NN + node];   // coalesced, L1/L2-hot
                float wot = adjT_out[j * NN + node];
                const float4* nj4 = reinterpret_cast<const float4*>(nrow + j * ROWP);
                float4 v0 = nj4[0];
                float4 v1 = nj4[1];
                float2 v2 = *reinterpret_cast<const float2*>(nrow + j * ROWP + 8);
                float v[HH] = {v0.x, v0.y, v0.z, v0.w, v1.x, v1.y, v1.z, v1.w, v2.x, v2.y};
                #pragma unroll
                for (int h = 0; h < HH; ++h) {
                    ai[h] = fmaf(win, v[h], ai[h]);
                    ao[h] = fmaf(wot, v[h], ao[h]);
                }
            }

            // ---- dense phase; weight indices are wave-uniform -> s_load ----
            float av[2 * HH];
            #pragma unroll
            for (int h = 0; h < HH; ++h) { av[h] = ai[h]; av[HH + h] = ao[h]; }

            // u3 = w3u . fn + b3u   (shared by zv and rv — reference's reuse "bug")
            float u3[HH];
            #pragma unroll
            for (int h = 0; h < HH; ++h) {
                float s = b3u[h];
                #pragma unroll
                for (int k = 0; k < HH; ++k) s = fmaf(w3u[h * HH + k], fn[k], s);
                u3[h] = s;
            }

            float zv[HH], rv[HH];
            #pragma unroll
            for (int h = 0; h < HH; ++h) {
                float s1 = b3w[h];
                float s2 = b4w[h];
                #pragma unroll
                for (int k = 0; k < 2 * HH; ++k) {
                    s1 = fmaf(w3w[h * 2 * HH + k], av[k], s1);
                    s2 = fmaf(w4w[h * 2 * HH + k], av[k], s2);
                }
                zv[h] = sigmoid_(s1 + u3[h]);
                rv[h] = sigmoid_(s2 + u3[h]);
            }

            float rf[HH];
            #pragma unroll
            for (int k = 0; k < HH; ++k) rf[k] = rv[k] * fn[k];

            float hv[HH];
            #pragma unroll
            for (int h = 0; h < HH; ++h) {
                float s = b5w[h] + b5u[h];
                #pragma unroll
                for (int k = 0; k < 2 * HH; ++k) s = fmaf(w5w[h * 2 * HH + k], av[k], s);
                #pragma unroll
                for (int k = 0; k < HH; ++k)     s = fmaf(w5u[h * HH + k], rf[k], s);
                hv[h] = tanh_(s);
            }

            #pragma unroll
            for (int h = 0; h < HH; ++h) fn[h] = fn[h] + zv[h] * (hv[h] - fn[h]);
        }

        __syncthreads();   // all LDS reads of this step done
        if (active) {
            #pragma unroll
            for (int h = 0; h < HH; ++h) nodes[bl][node][h] = fn[h];
        }
        __syncthreads();   // updated states visible for next step
    }

    // ---- output layer: tanh(concat(fn, x) @ wout^T + bout), plus fn itself ----
    if (active) {
        size_t row = (size_t)b * NN + node;
        const float* xr = x + row * HH;
        float xi[HH];
        #pragma unroll
        for (int h = 0; h < HH; ++h) xi[h] = xr[h];

        #pragma unroll
        for (int c = 0; c < OUTC; ++c) {
            float s = bout[c];
            #pragma unroll
            for (int k = 0; k < HH; ++k) s = fmaf(wout[c * 2 * HH + k],      fn[k], s);
            #pragma unroll
            for (int k = 0; k < HH; ++k) s = fmaf(wout[c * 2 * HH + HH + k], xi[k], s);
            out0[row * OUTC + c] = tanh_(s);
        }
        #pragma unroll
        for (int h = 0; h < HH; ++h) out_fn[row * HH + h] = fn[h];
    }
}

extern "C" void kernel_launch(void* const* d_in, const int* in_sizes, int n_in,
                              void* d_out, int out_size, void* d_ws, size_t ws_size,
                              hipStream_t stream) {
    const float* x       = (const float*)d_in[0];
    const float* in_adj  = (const float*)d_in[1];
    const float* out_adj = (const float*)d_in[2];
    const float* w3w = (const float*)d_in[3];
    const float* b3w = (const float*)d_in[4];
    const float* w3u = (const float*)d_in[5];
    const float* b3u = (const float*)d_in[6];
    const float* w4w = (const float*)d_in[7];
    const float* b4w = (const float*)d_in[8];
    const float* w5w = (const float*)d_in[9];
    const float* b5w = (const float*)d_in[10];
    const float* w5u = (const float*)d_in[11];
    const float* b5u = (const float*)d_in[12];
    const float* wout = (const float*)d_in[13];
    const float* bout = (const float*)d_in[14];

    float* adjT = (float*)d_ws;                      // 2*82*82 floats = 53.8 KB
    float* out0 = (float*)d_out;
    float* out_fn = out0 + (size_t)B_TOTAL * NN * OUTC;

    transpose_adj_kernel<<<(NN * NN + 255) / 256, 256, 0, stream>>>(in_adj, out_adj, adjT);

    int grid = (B_TOTAL + BPB - 1) / BPB;            // 2731
    ggnn_kernel<<<grid, THREADS, 0, stream>>>(
        x, adjT, w3w, b3w, w3u, b3u, w4w, b4w, w5w, b5w, w5u, b5u,
        wout, bout, out0, out_fn);
}